// Round 1
// baseline (519.662 us; speedup 1.0000x reference)
//
#include <hip/hip_runtime.h>

typedef unsigned short u16;
typedef unsigned int u32;
typedef __bf16 bf16;
typedef __attribute__((ext_vector_type(8))) bf16 bf16x8;
typedef __attribute__((ext_vector_type(4))) float f32x4;
typedef __attribute__((ext_vector_type(8))) u16 u16x8;

#define M_DIM 8192
#define N_DIM 4096
#define K_DIM 4096
#define BM 128
#define BN 128
#define BK 32

__device__ __forceinline__ u16 f2bf(float f) {
    // round-to-nearest-even f32 -> bf16 (inputs are finite)
    u32 u = __float_as_uint(f);
    u32 r = (u + 0x7fffu + ((u >> 16) & 1u)) >> 16;
    return (u16)r;
}

__device__ __forceinline__ float softplus_f(float x) {
    // numerically stable log(1+exp(x)) = max(x,0) + log1p(exp(-|x|))
    return fmaxf(x, 0.f) + log1pf(expf(-fabsf(x)));
}

__device__ __forceinline__ void gload_lds16(const void* g, void* l) {
    __builtin_amdgcn_global_load_lds(
        (const __attribute__((address_space(1))) void*)g,
        (__attribute__((address_space(3))) void*)l,
        16, 0, 0);
}

// ---------------- x -> bf16 cast ----------------
__global__ void conv_x_kernel(const float* __restrict__ x, u16* __restrict__ xb,
                              long long n8) {
    long long idx = blockIdx.x * (long long)blockDim.x + threadIdx.x;
    long long stride = gridDim.x * (long long)blockDim.x;
    for (long long i = idx; i < n8; i += stride) {
        const float4* xp = (const float4*)(x + i * 8);
        float4 a = xp[0], b = xp[1];
        u16x8 r;
        r[0] = f2bf(a.x); r[1] = f2bf(a.y); r[2] = f2bf(a.z); r[3] = f2bf(a.w);
        r[4] = f2bf(b.x); r[5] = f2bf(b.y); r[6] = f2bf(b.z); r[7] = f2bf(b.w);
        *(u16x8*)(xb + i * 8) = r;
    }
}

// ------- W sample + transpose: Wt[n][k] = bf16(w_loc + softplus(w_std)*eps_w) -------
__global__ void wconv_kernel(const float* __restrict__ w_loc,
                             const float* __restrict__ w_std,
                             const float* __restrict__ eps_w,
                             u16* __restrict__ wt) {
    __shared__ u16 t[64][66];   // +2 pad -> conflict-free transposed read
    const int kb = blockIdx.x & 63;
    const int nb = blockIdx.x >> 6;
    const int k0 = kb * 64, n0 = nb * 64;
    const int tx = threadIdx.x & 63;
    const int ty = threadIdx.x >> 6;   // 0..3
#pragma unroll
    for (int r = 0; r < 64; r += 4) {
        const size_t off = (size_t)(k0 + r + ty) * N_DIM + n0 + tx;
        float v = w_loc[off] + softplus_f(w_std[off]) * eps_w[off];
        t[r + ty][tx] = f2bf(v);
    }
    __syncthreads();
#pragma unroll
    for (int r = 0; r < 64; r += 4) {
        wt[(size_t)(n0 + r + ty) * K_DIM + k0 + tx] = t[tx][r + ty];
    }
}

// ---------------- bias ----------------
__global__ void bias_kernel(const float* __restrict__ b_loc,
                            const float* __restrict__ b_std,
                            const float* __restrict__ eps_b,
                            float* __restrict__ bias) {
    int i = blockIdx.x * blockDim.x + threadIdx.x;
    if (i < N_DIM) bias[i] = b_loc[i] + softplus_f(b_std[i]) * eps_b[i];
}

// ---------------- bf16 GEMM: C = Xb @ Wt^T + bias ----------------
// Xb [M][K] row-major bf16, Wt [N][K] row-major bf16 (i.e. B^T layout)
__global__ __launch_bounds__(256) void gemm_kernel(
    const u16* __restrict__ Xb, const u16* __restrict__ Wt,
    const float* __restrict__ bias, float* __restrict__ C) {
    __shared__ u16 As[2][BM * BK];   // 8 KB each buf
    __shared__ u16 Bs[2][BN * BK];

    const int tid = threadIdx.x;
    const int lane = tid & 63;
    const int wid = tid >> 6;        // 0..3
    const int wr = wid >> 1;         // wave row 0..1
    const int wc = wid & 1;          // wave col 0..1

    // XCD-aware bijective swizzle (nwg = 2048, 2048 % 8 == 0)
    const int nwg = gridDim.x;
    const int cpx = nwg >> 3;
    const int swz = (blockIdx.x & 7) * cpx + (blockIdx.x >> 3);
    const int NBN = N_DIM / BN;      // 32
    const int m0 = (swz / NBN) * BM;
    const int n0 = (swz % NBN) * BN;

    // staging geometry: 8 chunks of 1 KB per operand; chunk = 16 rows x 64 B
    const int crow = lane >> 2;          // 0..15 row within chunk
    const int ckel = (lane & 3) * 8;     // k-element offset (8 bf16 = 16 B)

    f32x4 acc[4][4] = {};

    const u16* Abase = Xb + (size_t)m0 * K_DIM;
    const u16* Bbase = Wt + (size_t)n0 * K_DIM;

    auto stage = [&](int buf, int kt) {
        const int k0 = kt * BK;
#pragma unroll
        for (int i = 0; i < 2; ++i) {
            const int c = wid * 2 + i;   // this wave's chunks: A and B
            const u16* gA = Abase + (size_t)(c * 16 + crow) * K_DIM + k0 + ckel;
            gload_lds16(gA, &As[buf][c * 512]);
            const u16* gB = Bbase + (size_t)(c * 16 + crow) * K_DIM + k0 + ckel;
            gload_lds16(gB, &Bs[buf][c * 512]);
        }
    };

    stage(0, 0);
    __syncthreads();

    const int fr = lane & 15;            // frag row (A) / col (B)
    const int fk = (lane >> 4) * 8;      // frag k element offset

    int cur = 0;
    const int NT = K_DIM / BK;           // 128
    for (int kt = 0; kt < NT; ++kt) {
        if (kt + 1 < NT) stage(cur ^ 1, kt + 1);

        bf16x8 af[4], bfr[4];
#pragma unroll
        for (int m = 0; m < 4; ++m)
            af[m] = *(const bf16x8*)&As[cur][(wr * 64 + m * 16 + fr) * BK + fk];
#pragma unroll
        for (int n = 0; n < 4; ++n)
            bfr[n] = *(const bf16x8*)&Bs[cur][(wc * 64 + n * 16 + fr) * BK + fk];

#pragma unroll
        for (int m = 0; m < 4; ++m)
#pragma unroll
            for (int n = 0; n < 4; ++n)
                acc[m][n] = __builtin_amdgcn_mfma_f32_16x16x32_bf16(
                    af[m], bfr[n], acc[m][n], 0, 0, 0);

        __syncthreads();   // drains vmcnt for the prefetch + protects LDS reuse
        cur ^= 1;
    }

    // epilogue: C/D layout col=lane&15, row=(lane>>4)*4+reg
    const int orow0 = m0 + wr * 64;
    const int ocol0 = n0 + wc * 64;
    float bv[4];
#pragma unroll
    for (int n = 0; n < 4; ++n) bv[n] = bias[ocol0 + n * 16 + fr];
#pragma unroll
    for (int m = 0; m < 4; ++m) {
#pragma unroll
        for (int n = 0; n < 4; ++n) {
#pragma unroll
            for (int j = 0; j < 4; ++j) {
                const int row = orow0 + m * 16 + (lane >> 4) * 4 + j;
                const int col = ocol0 + n * 16 + fr;
                C[(size_t)row * N_DIM + col] = acc[m][n][j] + bv[n];
            }
        }
    }
}

extern "C" void kernel_launch(void* const* d_in, const int* in_sizes, int n_in,
                              void* d_out, int out_size, void* d_ws, size_t ws_size,
                              hipStream_t stream) {
    const float* x     = (const float*)d_in[0];
    const float* w_loc = (const float*)d_in[1];
    const float* w_std = (const float*)d_in[2];
    const float* b_loc = (const float*)d_in[3];
    const float* b_std = (const float*)d_in[4];
    const float* eps_w = (const float*)d_in[5];
    const float* eps_b = (const float*)d_in[6];
    float* out = (float*)d_out;

    char* ws = (char*)d_ws;
    u16* Xb   = (u16*)ws;                                            // 64 MB
    u16* Wt   = (u16*)(ws + (size_t)M_DIM * K_DIM * 2);              // 32 MB
    float* bv = (float*)(ws + (size_t)M_DIM * K_DIM * 2
                            + (size_t)N_DIM * K_DIM * 2);            // 16 KB

    conv_x_kernel<<<2048, 256, 0, stream>>>(x, Xb, (long long)M_DIM * K_DIM / 8);
    wconv_kernel<<<(K_DIM / 64) * (N_DIM / 64), 256, 0, stream>>>(w_loc, w_std, eps_w, Wt);
    bias_kernel<<<N_DIM / 256, 256, 0, stream>>>(b_loc, b_std, eps_b, bv);
    gemm_kernel<<<(M_DIM / BM) * (N_DIM / BN), 256, 0, stream>>>(Xb, Wt, bv, out);
}

// Round 2
// 366.241 us; speedup vs baseline: 1.4189x; 1.4189x over previous
//
#include <hip/hip_runtime.h>

typedef unsigned short u16;
typedef unsigned int u32;
typedef __bf16 bf16;
typedef __attribute__((ext_vector_type(8))) bf16 bf16x8;
typedef __attribute__((ext_vector_type(4))) float f32x4;
typedef __attribute__((ext_vector_type(8))) u16 u16x8;

#define M_DIM 8192
#define N_DIM 4096
#define K_DIM 4096
#define NT    (K_DIM / 32)   // 128 K-tiles of 32

__device__ __forceinline__ u16 f2bf(float f) {
    u32 u = __float_as_uint(f);
    u32 r = (u + 0x7fffu + ((u >> 16) & 1u)) >> 16;
    return (u16)r;
}

__device__ __forceinline__ float softplus_f(float x) {
    return fmaxf(x, 0.f) + log1pf(expf(-fabsf(x)));
}

__device__ __forceinline__ void gload_lds16(const void* g, void* l) {
    __builtin_amdgcn_global_load_lds(
        (const __attribute__((address_space(1))) void*)g,
        (__attribute__((address_space(3))) void*)l,
        16, 0, 0);
}

// ---------------- x -> bf16 cast ----------------
__global__ void conv_x_kernel(const float* __restrict__ x, u16* __restrict__ xb,
                              long long n8) {
    long long idx = blockIdx.x * (long long)blockDim.x + threadIdx.x;
    long long stride = gridDim.x * (long long)blockDim.x;
    for (long long i = idx; i < n8; i += stride) {
        const float4* xp = (const float4*)(x + i * 8);
        float4 a = xp[0], b = xp[1];
        u16x8 r;
        r[0] = f2bf(a.x); r[1] = f2bf(a.y); r[2] = f2bf(a.z); r[3] = f2bf(a.w);
        r[4] = f2bf(b.x); r[5] = f2bf(b.y); r[6] = f2bf(b.z); r[7] = f2bf(b.w);
        *(u16x8*)(xb + i * 8) = r;
    }
}

// ------- W sample + transpose: Wt[n][k] = bf16(w_loc + softplus(w_std)*eps_w) -------
__global__ void wconv_kernel(const float* __restrict__ w_loc,
                             const float* __restrict__ w_std,
                             const float* __restrict__ eps_w,
                             u16* __restrict__ wt) {
    __shared__ u16 t[64][66];
    const int kb = blockIdx.x & 63;
    const int nb = blockIdx.x >> 6;
    const int k0 = kb * 64, n0 = nb * 64;
    const int tx = threadIdx.x & 63;
    const int ty = threadIdx.x >> 6;
#pragma unroll
    for (int r = 0; r < 64; r += 4) {
        const size_t off = (size_t)(k0 + r + ty) * N_DIM + n0 + tx;
        float v = w_loc[off] + softplus_f(w_std[off]) * eps_w[off];
        t[r + ty][tx] = f2bf(v);
    }
    __syncthreads();
#pragma unroll
    for (int r = 0; r < 64; r += 4) {
        wt[(size_t)(n0 + r + ty) * K_DIM + k0 + tx] = t[tx][r + ty];
    }
}

// ---------------- bias ----------------
__global__ void bias_kernel(const float* __restrict__ b_loc,
                            const float* __restrict__ b_std,
                            const float* __restrict__ eps_b,
                            float* __restrict__ bias) {
    int i = blockIdx.x * blockDim.x + threadIdx.x;
    if (i < N_DIM) bias[i] = b_loc[i] + softplus_f(b_std[i]) * eps_b[i];
}

// ---------------- 256x256 phase-interleaved bf16 GEMM ----------------
// C[M][N] = Xb[M][K] @ Wt[N][K]^T + bias
// 8 waves (2M x 4N), per-wave 128x64 out. 2 phases per K-tile (BK=32),
// counted vmcnt (never 0 in steady state), setprio around MFMA clusters.
// LDS 64 KiB: A/B each 2 dbuf x 2 half x [128][32] bf16.
// Swizzle: colbyte ^= (row&3)<<4 applied on read AND pre-applied to the
// global source of global_load_lds (linear DMA dest) — rule #21.
__global__ __launch_bounds__(512, 2) void gemm_kernel(
    const u16* __restrict__ Xb, const u16* __restrict__ Wt,
    const float* __restrict__ bias, float* __restrict__ C) {
    __shared__ __align__(16) u16 lds[32768];   // 64 KiB: A at 0, B at 16384

    const int tid = threadIdx.x;
    const int l  = tid & 63;
    const int w  = tid >> 6;          // wave 0..7
    const int wm = w >> 2;            // 0..1
    const int wn = w & 3;             // 0..3

    // T1: XCD-bijective swizzle (512 blocks, 512 % 8 == 0)
    const int swz = (blockIdx.x & 7) * 64 + (blockIdx.x >> 3);
    const int m0 = (swz >> 4) * 256;  // 32 M-tiles
    const int n0 = (swz & 15) * 256;  // 16 N-tiles

    const u16* Ab = Xb + (size_t)m0 * K_DIM;
    const u16* Bb = Wt + (size_t)n0 * K_DIM;

    // stage geometry: one gload_lds per thread covers one 8 KiB half-tile
    // thread (w,l): LDS bytes w*1024 + l*16 -> row = w*16 + (l>>2),
    // src col pre-swizzled: 16*((l&3) ^ ((l>>2)&3)) bytes
    const int sr = w * 16 + (l >> 2);
    const int sc = ((l & 3) ^ ((l >> 2) & 3)) << 3;   // elements

    // read geometry: frag k-slot hi=l>>4, row fr=l&15; swizzled col elems
    const int fr = l & 15, hi = l >> 4;
    const int ce = ((hi ^ (l & 3)) << 3);             // elements

    auto stageA = [&](int buf, int half, int kt) {
        const u16* g = Ab + (size_t)(half * 128 + sr) * K_DIM + kt * 32 + sc;
        gload_lds16(g, &lds[buf * 8192 + half * 4096 + w * 512]);
    };
    auto stageB = [&](int buf, int half, int kt) {
        const u16* g = Bb + (size_t)(half * 128 + sr) * K_DIM + kt * 32 + sc;
        gload_lds16(g, &lds[16384 + buf * 8192 + half * 4096 + w * 512]);
    };
    auto ldA = [&](int buf, int m) -> bf16x8 {   // m 0..7 within wave's half
        return *(const bf16x8*)&lds[buf * 8192 + wm * 4096 + (m * 16 + fr) * 32 + ce];
    };
    auto ldB = [&](int buf, int n) -> bf16x8 {   // n 0..3
        return *(const bf16x8*)&lds[16384 + buf * 8192 + (wn >> 1) * 4096
                                    + ((wn & 1) * 64 + n * 16 + fr) * 32 + ce];
    };

    f32x4 acc[8][4] = {};

    // ---- prologue: tile0 full + B halves of tile1 in flight ----
    stageA(0, 0, 0); stageA(0, 1, 0); stageB(0, 0, 0); stageB(0, 1, 0);
    stageB(1, 0, 1); stageB(1, 1, 1);
    asm volatile("s_waitcnt vmcnt(2)" ::: "memory");   // tile0 resident
    __builtin_amdgcn_sched_barrier(0);
    __builtin_amdgcn_s_barrier();

    for (int t = 0; t < NT; ++t) {
        const int buf = t & 1;

        // ======== phase 0: B(all) + A(m0..3) reads | stage A(t+1) | MFMA q0 ========
        bf16x8 b[4], a[4];
        b[0] = ldB(buf, 0); b[1] = ldB(buf, 1); b[2] = ldB(buf, 2); b[3] = ldB(buf, 3);
        a[0] = ldA(buf, 0); a[1] = ldA(buf, 1); a[2] = ldA(buf, 2); a[3] = ldA(buf, 3);
        if (t + 1 < NT) { stageA(buf ^ 1, 0, t + 1); stageA(buf ^ 1, 1, t + 1); }
        __builtin_amdgcn_s_barrier();
        asm volatile("s_waitcnt lgkmcnt(0)" ::: "memory");
        __builtin_amdgcn_sched_barrier(0);
        __builtin_amdgcn_s_setprio(1);
#pragma unroll
        for (int i = 0; i < 4; ++i)
#pragma unroll
            for (int n = 0; n < 4; ++n)
                acc[i][n] = __builtin_amdgcn_mfma_f32_16x16x32_bf16(
                    a[i], b[n], acc[i][n], 0, 0, 0);
        __builtin_amdgcn_s_setprio(0);
        __builtin_amdgcn_s_barrier();

        // ======== phase 1: A(m4..7) reads | stage B(t+2) | MFMA q1 ========
        a[0] = ldA(buf, 4); a[1] = ldA(buf, 5); a[2] = ldA(buf, 6); a[3] = ldA(buf, 7);
        if (t + 2 < NT) { stageB(buf, 0, t + 2); stageB(buf, 1, t + 2); }
        __builtin_amdgcn_s_barrier();
        asm volatile("s_waitcnt lgkmcnt(0)" ::: "memory");
        __builtin_amdgcn_sched_barrier(0);
        __builtin_amdgcn_s_setprio(1);
#pragma unroll
        for (int i = 0; i < 4; ++i)
#pragma unroll
            for (int n = 0; n < 4; ++n)
                acc[4 + i][n] = __builtin_amdgcn_mfma_f32_16x16x32_bf16(
                    a[i], b[n], acc[4 + i][n], 0, 0, 0);
        __builtin_amdgcn_s_setprio(0);
        // counted drain: leave the 2 newest stages (B(t+2)) in flight
        if (t + 2 < NT) {
            asm volatile("s_waitcnt vmcnt(2)" ::: "memory");
        } else if (t + 1 < NT) {
            asm volatile("s_waitcnt vmcnt(0)" ::: "memory");
        }
        __builtin_amdgcn_sched_barrier(0);
        __builtin_amdgcn_s_barrier();
    }

    // ---- epilogue ----
    const int orow0 = m0 + wm * 128;
    const int ocol0 = n0 + wn * 64;
    float bv[4];
#pragma unroll
    for (int n = 0; n < 4; ++n) bv[n] = bias[ocol0 + n * 16 + fr];
#pragma unroll
    for (int m = 0; m < 8; ++m)
#pragma unroll
        for (int n = 0; n < 4; ++n)
#pragma unroll
            for (int j = 0; j < 4; ++j)
                C[(size_t)(orow0 + m * 16 + hi * 4 + j) * N_DIM
                  + ocol0 + n * 16 + fr] = acc[m][n][j] + bv[n];
}

extern "C" void kernel_launch(void* const* d_in, const int* in_sizes, int n_in,
                              void* d_out, int out_size, void* d_ws, size_t ws_size,
                              hipStream_t stream) {
    const float* x     = (const float*)d_in[0];
    const float* w_loc = (const float*)d_in[1];
    const float* w_std = (const float*)d_in[2];
    const float* b_loc = (const float*)d_in[3];
    const float* b_std = (const float*)d_in[4];
    const float* eps_w = (const float*)d_in[5];
    const float* eps_b = (const float*)d_in[6];
    float* out = (float*)d_out;

    char* ws = (char*)d_ws;
    u16* Xb   = (u16*)ws;                                            // 64 MB
    u16* Wt   = (u16*)(ws + (size_t)M_DIM * K_DIM * 2);              // 32 MB
    float* bv = (float*)(ws + (size_t)M_DIM * K_DIM * 2
                            + (size_t)N_DIM * K_DIM * 2);            // 16 KB

    conv_x_kernel<<<2048, 256, 0, stream>>>(x, Xb, (long long)M_DIM * K_DIM / 8);
    wconv_kernel<<<(K_DIM / 64) * (N_DIM / 64), 256, 0, stream>>>(w_loc, w_std, eps_w, Wt);
    bias_kernel<<<N_DIM / 256, 256, 0, stream>>>(b_loc, b_std, eps_b, bv);
    gemm_kernel<<<(M_DIM / 256) * (N_DIM / 256), 512, 0, stream>>>(Xb, Wt, bv, out);
}

// Round 3
// 354.909 us; speedup vs baseline: 1.4642x; 1.0319x over previous
//
#include <hip/hip_runtime.h>

typedef unsigned short u16;
typedef unsigned int u32;
typedef __bf16 bf16;
typedef __attribute__((ext_vector_type(8))) bf16 bf16x8;
typedef __attribute__((ext_vector_type(4))) float f32x4;
typedef __attribute__((ext_vector_type(8))) u16 u16x8;

#define M_DIM 8192
#define N_DIM 4096
#define K_DIM 4096
#define NT    (K_DIM / 32)   // 128 K-tiles of 32

__device__ __forceinline__ u16 f2bf(float f) {
    u32 u = __float_as_uint(f);
    u32 r = (u + 0x7fffu + ((u >> 16) & 1u)) >> 16;
    return (u16)r;
}

__device__ __forceinline__ float softplus_f(float x) {
    return fmaxf(x, 0.f) + log1pf(expf(-fabsf(x)));
}

__device__ __forceinline__ void gload_lds16(const void* g, void* l) {
    __builtin_amdgcn_global_load_lds(
        (const __attribute__((address_space(1))) void*)g,
        (__attribute__((address_space(3))) void*)l,
        16, 0, 0);
}

// ---------------- x -> bf16 cast ----------------
__global__ void conv_x_kernel(const float* __restrict__ x, u16* __restrict__ xb,
                              long long n8) {
    long long idx = blockIdx.x * (long long)blockDim.x + threadIdx.x;
    long long stride = gridDim.x * (long long)blockDim.x;
    for (long long i = idx; i < n8; i += stride) {
        const float4* xp = (const float4*)(x + i * 8);
        float4 a = xp[0], b = xp[1];
        u16x8 r;
        r[0] = f2bf(a.x); r[1] = f2bf(a.y); r[2] = f2bf(a.z); r[3] = f2bf(a.w);
        r[4] = f2bf(b.x); r[5] = f2bf(b.y); r[6] = f2bf(b.z); r[7] = f2bf(b.w);
        *(u16x8*)(xb + i * 8) = r;
    }
}

// ------- W sample + transpose: Wt[n][k] = bf16(w_loc + softplus(w_std)*eps_w) -------
__global__ void wconv_kernel(const float* __restrict__ w_loc,
                             const float* __restrict__ w_std,
                             const float* __restrict__ eps_w,
                             u16* __restrict__ wt) {
    __shared__ u16 t[64][66];
    const int kb = blockIdx.x & 63;
    const int nb = blockIdx.x >> 6;
    const int k0 = kb * 64, n0 = nb * 64;
    const int tx = threadIdx.x & 63;
    const int ty = threadIdx.x >> 6;
#pragma unroll
    for (int r = 0; r < 64; r += 4) {
        const size_t off = (size_t)(k0 + r + ty) * N_DIM + n0 + tx;
        float v = w_loc[off] + softplus_f(w_std[off]) * eps_w[off];
        t[r + ty][tx] = f2bf(v);
    }
    __syncthreads();
#pragma unroll
    for (int r = 0; r < 64; r += 4) {
        wt[(size_t)(n0 + r + ty) * K_DIM + k0 + tx] = t[tx][r + ty];
    }
}

// ---------------- bias ----------------
__global__ void bias_kernel(const float* __restrict__ b_loc,
                            const float* __restrict__ b_std,
                            const float* __restrict__ eps_b,
                            float* __restrict__ bias) {
    int i = blockIdx.x * blockDim.x + threadIdx.x;
    if (i < N_DIM) bias[i] = b_loc[i] + softplus_f(b_std[i]) * eps_b[i];
}

// ---------------- 256x256 phase-interleaved bf16 GEMM ----------------
// C[M][N] = Xb[M][K] @ Wt[N][K]^T + bias
// 8 waves (2M x 4N), per-wave 128x64 out. 2 phases per K-tile (BK=32),
// counted vmcnt (never 0 in steady state), setprio around MFMA clusters.
// LDS 64 KiB: A/B each 2 dbuf x 2 half x [128][32] bf16.
// Swizzle (derived conflict-free): 16B-granule g = hi ^ ((row>>1)&3).
// Within any aligned 8-row window the 4 even rows give (row>>1)&3 =
// {0,1,2,3} distinct -> bank-quads 4*(row&1)+g all 8 distinct per
// 8-lane group. Involution -> same XOR pre-applied to the global source
// of global_load_lds (linear DMA dest, rule #21) and to the ds_read col.
__global__ __launch_bounds__(512, 2) void gemm_kernel(
    const u16* __restrict__ Xb, const u16* __restrict__ Wt,
    const float* __restrict__ bias, float* __restrict__ C) {
    __shared__ __align__(16) u16 lds[32768];   // 64 KiB: A at 0, B at 16384

    const int tid = threadIdx.x;
    const int l  = tid & 63;
    const int w  = tid >> 6;          // wave 0..7
    const int wm = w >> 2;            // 0..1
    const int wn = w & 3;             // 0..3

    // T1: XCD-bijective swizzle (512 blocks, 512 % 8 == 0)
    const int swz = (blockIdx.x & 7) * 64 + (blockIdx.x >> 3);
    const int m0 = (swz >> 4) * 256;  // 32 M-tiles
    const int n0 = (swz & 15) * 256;  // 16 N-tiles

    const u16* Ab = Xb + (size_t)m0 * K_DIM;
    const u16* Bb = Wt + (size_t)n0 * K_DIM;

    // stage geometry: thread (w,l) -> LDS byte w*1024 + l*16
    //   row = w*16 + (l>>2), LDS granule p = l&3
    //   source granule q = p ^ ((row>>1)&3) = (l&3) ^ ((l>>3)&3)
    const int sr = w * 16 + (l >> 2);
    const int sc = ((l & 3) ^ ((l >> 3) & 3)) << 3;   // elements

    // read geometry: fr = row-within-16 (base rows are multiples of 16),
    // hi = k-slot; granule = hi ^ ((fr>>1)&3)
    const int fr = l & 15, hi = l >> 4;
    const int ce = ((hi ^ ((fr >> 1) & 3)) << 3);     // elements

    auto stageA = [&](int buf, int half, int kt) {
        const u16* g = Ab + (size_t)(half * 128 + sr) * K_DIM + kt * 32 + sc;
        gload_lds16(g, &lds[buf * 8192 + half * 4096 + w * 512]);
    };
    auto stageB = [&](int buf, int half, int kt) {
        const u16* g = Bb + (size_t)(half * 128 + sr) * K_DIM + kt * 32 + sc;
        gload_lds16(g, &lds[16384 + buf * 8192 + half * 4096 + w * 512]);
    };
    auto ldA = [&](int buf, int m) -> bf16x8 {   // m 0..7 within wave's half
        return *(const bf16x8*)&lds[buf * 8192 + wm * 4096 + (m * 16 + fr) * 32 + ce];
    };
    auto ldB = [&](int buf, int n) -> bf16x8 {   // n 0..3
        return *(const bf16x8*)&lds[16384 + buf * 8192 + (wn >> 1) * 4096
                                    + ((wn & 1) * 64 + n * 16 + fr) * 32 + ce];
    };

    f32x4 acc[8][4] = {};

    // ---- prologue: tile0 full + B halves of tile1 in flight ----
    stageA(0, 0, 0); stageA(0, 1, 0); stageB(0, 0, 0); stageB(0, 1, 0);
    stageB(1, 0, 1); stageB(1, 1, 1);
    asm volatile("s_waitcnt vmcnt(2)" ::: "memory");   // tile0 resident
    __builtin_amdgcn_sched_barrier(0);
    __builtin_amdgcn_s_barrier();

    for (int t = 0; t < NT; ++t) {
        const int buf = t & 1;

        // ======== phase 0: B(all) + A(m0..3) reads | stage A(t+1) | MFMA q0 ========
        bf16x8 b[4], a[4];
        b[0] = ldB(buf, 0); b[1] = ldB(buf, 1); b[2] = ldB(buf, 2); b[3] = ldB(buf, 3);
        a[0] = ldA(buf, 0); a[1] = ldA(buf, 1); a[2] = ldA(buf, 2); a[3] = ldA(buf, 3);
        if (t + 1 < NT) { stageA(buf ^ 1, 0, t + 1); stageA(buf ^ 1, 1, t + 1); }
        __builtin_amdgcn_s_barrier();
        asm volatile("s_waitcnt lgkmcnt(0)" ::: "memory");
        __builtin_amdgcn_sched_barrier(0);
        __builtin_amdgcn_s_setprio(1);
#pragma unroll
        for (int i = 0; i < 4; ++i)
#pragma unroll
            for (int n = 0; n < 4; ++n)
                acc[i][n] = __builtin_amdgcn_mfma_f32_16x16x32_bf16(
                    a[i], b[n], acc[i][n], 0, 0, 0);
        __builtin_amdgcn_s_setprio(0);
        __builtin_amdgcn_s_barrier();

        // ======== phase 1: A(m4..7) reads | stage B(t+2) | MFMA q1 ========
        a[0] = ldA(buf, 4); a[1] = ldA(buf, 5); a[2] = ldA(buf, 6); a[3] = ldA(buf, 7);
        if (t + 2 < NT) { stageB(buf, 0, t + 2); stageB(buf, 1, t + 2); }
        __builtin_amdgcn_s_barrier();
        asm volatile("s_waitcnt lgkmcnt(0)" ::: "memory");
        __builtin_amdgcn_sched_barrier(0);
        __builtin_amdgcn_s_setprio(1);
#pragma unroll
        for (int i = 0; i < 4; ++i)
#pragma unroll
            for (int n = 0; n < 4; ++n)
                acc[4 + i][n] = __builtin_amdgcn_mfma_f32_16x16x32_bf16(
                    a[i], b[n], acc[4 + i][n], 0, 0, 0);
        __builtin_amdgcn_s_setprio(0);
        // counted drain: leave the 2 newest stages (B(t+2)) in flight
        if (t + 2 < NT) {
            asm volatile("s_waitcnt vmcnt(2)" ::: "memory");
        } else if (t + 1 < NT) {
            asm volatile("s_waitcnt vmcnt(0)" ::: "memory");
        }
        __builtin_amdgcn_sched_barrier(0);
        __builtin_amdgcn_s_barrier();
    }

    // ---- epilogue ----
    const int orow0 = m0 + wm * 128;
    const int ocol0 = n0 + wn * 64;
    float bv[4];
#pragma unroll
    for (int n = 0; n < 4; ++n) bv[n] = bias[ocol0 + n * 16 + fr];
#pragma unroll
    for (int m = 0; m < 8; ++m)
#pragma unroll
        for (int n = 0; n < 4; ++n)
#pragma unroll
            for (int j = 0; j < 4; ++j)
                C[(size_t)(orow0 + m * 16 + hi * 4 + j) * N_DIM
                  + ocol0 + n * 16 + fr] = acc[m][n][j] + bv[n];
}

extern "C" void kernel_launch(void* const* d_in, const int* in_sizes, int n_in,
                              void* d_out, int out_size, void* d_ws, size_t ws_size,
                              hipStream_t stream) {
    const float* x     = (const float*)d_in[0];
    const float* w_loc = (const float*)d_in[1];
    const float* w_std = (const float*)d_in[2];
    const float* b_loc = (const float*)d_in[3];
    const float* b_std = (const float*)d_in[4];
    const float* eps_w = (const float*)d_in[5];
    const float* eps_b = (const float*)d_in[6];
    float* out = (float*)d_out;

    char* ws = (char*)d_ws;
    u16* Xb   = (u16*)ws;                                            // 64 MB
    u16* Wt   = (u16*)(ws + (size_t)M_DIM * K_DIM * 2);              // 32 MB
    float* bv = (float*)(ws + (size_t)M_DIM * K_DIM * 2
                            + (size_t)N_DIM * K_DIM * 2);            // 16 KB

    conv_x_kernel<<<2048, 256, 0, stream>>>(x, Xb, (long long)M_DIM * K_DIM / 8);
    wconv_kernel<<<(K_DIM / 64) * (N_DIM / 64), 256, 0, stream>>>(w_loc, w_std, eps_w, Wt);
    bias_kernel<<<N_DIM / 256, 256, 0, stream>>>(b_loc, b_std, eps_b, bv);
    gemm_kernel<<<(M_DIM / 256) * (N_DIM / 256), 512, 0, stream>>>(Xb, Wt, bv, out);
}

// Round 4
// 354.605 us; speedup vs baseline: 1.4655x; 1.0009x over previous
//
#include <hip/hip_runtime.h>

typedef unsigned short u16;
typedef unsigned int u32;
typedef __bf16 bf16;
typedef __attribute__((ext_vector_type(8))) bf16 bf16x8;
typedef __attribute__((ext_vector_type(4))) float f32x4;
typedef __attribute__((ext_vector_type(8))) u16 u16x8;

#define M_DIM 8192
#define N_DIM 4096
#define K_DIM 4096
#define NTK   (K_DIM / 64)   // 64 K-tiles of 64

__device__ __forceinline__ u16 f2bf(float f) {
    u32 u = __float_as_uint(f);
    u32 r = (u + 0x7fffu + ((u >> 16) & 1u)) >> 16;
    return (u16)r;
}

__device__ __forceinline__ float softplus_f(float x) {
    return fmaxf(x, 0.f) + log1pf(expf(-fabsf(x)));
}

__device__ __forceinline__ void gload_lds16(const void* g, void* l) {
    __builtin_amdgcn_global_load_lds(
        (const __attribute__((address_space(1))) void*)g,
        (__attribute__((address_space(3))) void*)l,
        16, 0, 0);
}

// ---------------- x -> bf16 cast ----------------
__global__ void conv_x_kernel(const float* __restrict__ x, u16* __restrict__ xb,
                              long long n8) {
    long long idx = blockIdx.x * (long long)blockDim.x + threadIdx.x;
    long long stride = gridDim.x * (long long)blockDim.x;
    for (long long i = idx; i < n8; i += stride) {
        const float4* xp = (const float4*)(x + i * 8);
        float4 a = xp[0], b = xp[1];
        u16x8 r;
        r[0] = f2bf(a.x); r[1] = f2bf(a.y); r[2] = f2bf(a.z); r[3] = f2bf(a.w);
        r[4] = f2bf(b.x); r[5] = f2bf(b.y); r[6] = f2bf(b.z); r[7] = f2bf(b.w);
        *(u16x8*)(xb + i * 8) = r;
    }
}

// ------- W sample + transpose: Wt[n][k] = bf16(w_loc + softplus(w_std)*eps_w) -------
__global__ void wconv_kernel(const float* __restrict__ w_loc,
                             const float* __restrict__ w_std,
                             const float* __restrict__ eps_w,
                             u16* __restrict__ wt) {
    __shared__ u16 t[64][66];
    const int kb = blockIdx.x & 63;
    const int nb = blockIdx.x >> 6;
    const int k0 = kb * 64, n0 = nb * 64;
    const int tx = threadIdx.x & 63;
    const int ty = threadIdx.x >> 6;
#pragma unroll
    for (int r = 0; r < 64; r += 4) {
        const size_t off = (size_t)(k0 + r + ty) * N_DIM + n0 + tx;
        float v = w_loc[off] + softplus_f(w_std[off]) * eps_w[off];
        t[r + ty][tx] = f2bf(v);
    }
    __syncthreads();
#pragma unroll
    for (int r = 0; r < 64; r += 4) {
        wt[(size_t)(n0 + r + ty) * K_DIM + k0 + tx] = t[tx][r + ty];
    }
}

// ---------------- bias ----------------
__global__ void bias_kernel(const float* __restrict__ b_loc,
                            const float* __restrict__ b_std,
                            const float* __restrict__ eps_b,
                            float* __restrict__ bias) {
    int i = blockIdx.x * blockDim.x + threadIdx.x;
    if (i < N_DIM) bias[i] = b_loc[i] + softplus_f(b_std[i]) * eps_b[i];
}

#define MFMA_Q(O, AV, BV)                                                    \
    _Pragma("unroll") for (int i_ = 0; i_ < 4; ++i_)                         \
    _Pragma("unroll") for (int n_ = 0; n_ < 4; ++n_)                         \
        acc[(O) + i_][n_] = __builtin_amdgcn_mfma_f32_16x16x32_bf16(         \
            AV[i_], BV[n_], acc[(O) + i_][n_], 0, 0, 0);

#define PH_SYNC_IN()                                                         \
    __builtin_amdgcn_s_barrier();                                            \
    asm volatile("s_waitcnt lgkmcnt(0)" ::: "memory");                       \
    __builtin_amdgcn_sched_barrier(0);                                       \
    __builtin_amdgcn_s_setprio(1);

#define PH_SYNC_OUT()                                                        \
    __builtin_amdgcn_s_setprio(0);                                           \
    __builtin_amdgcn_s_barrier();

// ---------------- 256x256 4-phase/K-tile bf16 GEMM (m201-style) ----------------
// C[M][N] = Xb[M][K] @ Wt[N][K]^T + bias. BK=64, 8 waves (2Mx4N), 128 KiB LDS.
// Per tile u: phA{B ks01 + A ks0 m0-3 | stage A(u+1)}, phB{A ks0 m4-7 | stage
// B(u+2)}, phC{A ks1 m0-3}, phD{A ks1 m4-7 | vmcnt(4)}. vmcnt(4) leaves only
// the newest 4-load stage (B(u+2)) in flight => A(u+1),B(u+1) resident; never
// drains to 0 mid-loop. Swizzle (128B rows): granule g=(ks*4+hi)^(row&7);
// DMA source pre-swizzled q=(tid&7)^((tid>>3)&7) (rule #21).
__global__ __launch_bounds__(512, 2) void gemm_kernel(
    const u16* __restrict__ Xb, const u16* __restrict__ Wt,
    const float* __restrict__ bias, float* __restrict__ C) {
    extern __shared__ u16 lds[];   // 128 KiB: A [2][256][64] at 0, B at 32768

    const int tid = threadIdx.x;
    const int l  = tid & 63;
    const int w  = tid >> 6;          // wave 0..7
    const int wm = w >> 2;            // 0..1
    const int wn = w & 3;             // 0..3

    // T1: XCD-bijective swizzle (512 blocks, 512 % 8 == 0)
    const int swz = (blockIdx.x & 7) * 64 + (blockIdx.x >> 3);
    const int m0 = (swz >> 4) * 256;  // 32 M-tiles
    const int n0 = (swz & 15) * 256;  // 16 N-tiles

    const u16* Ab = Xb + (size_t)m0 * K_DIM;
    const u16* Bb = Wt + (size_t)n0 * K_DIM;

    // staging: shot s covers rows s*64 + tid/8, granule tid&7 (linear dest)
    const int srow = tid >> 3;                        // 0..63
    const int sq   = ((tid & 7) ^ (srow & 7)) * 8;    // pre-swizzled col elems

    // reads: fr = row-within-16, hi = k-granule
    const int fr = l & 15, hi = l >> 4;
    const int cg0 = (hi ^ (fr & 7)) * 8;              // ks0 col elems
    const int cg1 = cg0 ^ 32;                         // ks1

    auto stageA = [&](int u) {
#pragma unroll
        for (int s = 0; s < 4; ++s) {
            const u16* g = Ab + (size_t)(s * 64 + srow) * K_DIM + u * 64 + sq;
            gload_lds16(g, &lds[(u & 1) * 16384 + s * 4096 + tid * 8]);
        }
    };
    auto stageB = [&](int u) {
#pragma unroll
        for (int s = 0; s < 4; ++s) {
            const u16* g = Bb + (size_t)(s * 64 + srow) * K_DIM + u * 64 + sq;
            gload_lds16(g, &lds[32768 + (u & 1) * 16384 + s * 4096 + tid * 8]);
        }
    };

    f32x4 acc[8][4] = {};

    // ---- prologue: A(0), B(0), B(1) in flight; wait A(0),B(0) ----
    stageA(0); stageB(0); stageB(1);
    asm volatile("s_waitcnt vmcnt(4)" ::: "memory");
    __builtin_amdgcn_sched_barrier(0);
    __builtin_amdgcn_s_barrier();

    for (int u = 0; u < NTK; ++u) {
        const int bo = (u & 1) * 16384;           // A buf base (elems)
        const int bB = 32768 + bo;                // B buf base
        const int arow = bo + (wm * 128 + fr) * 64;
        const int brow = bB + (wn * 64 + fr) * 64;
        bf16x8 a[4], b0[4], b1[4];

        // ---- phase A: B ks0+ks1 (8 reads) + A ks0 m0-3 | stage A(u+1) | q0*ks0
#pragma unroll
        for (int n = 0; n < 4; ++n) {
            b0[n] = *(const bf16x8*)&lds[brow + n * 1024 + cg0];
            b1[n] = *(const bf16x8*)&lds[brow + n * 1024 + cg1];
        }
#pragma unroll
        for (int m = 0; m < 4; ++m)
            a[m] = *(const bf16x8*)&lds[arow + m * 1024 + cg0];
        if (u + 1 < NTK) stageA(u + 1);
        PH_SYNC_IN();
        MFMA_Q(0, a, b0);
        PH_SYNC_OUT();

        // ---- phase B: A ks0 m4-7 | stage B(u+2) | q1*ks0
#pragma unroll
        for (int m = 0; m < 4; ++m)
            a[m] = *(const bf16x8*)&lds[arow + (m + 4) * 1024 + cg0];
        if (u + 2 < NTK) stageB(u + 2);
        PH_SYNC_IN();
        MFMA_Q(4, a, b0);
        PH_SYNC_OUT();

        // ---- phase C: A ks1 m0-3 | q0*ks1
#pragma unroll
        for (int m = 0; m < 4; ++m)
            a[m] = *(const bf16x8*)&lds[arow + m * 1024 + cg1];
        PH_SYNC_IN();
        MFMA_Q(0, a, b1);
        PH_SYNC_OUT();

        // ---- phase D: A ks1 m4-7 | q1*ks1 | counted drain
#pragma unroll
        for (int m = 0; m < 4; ++m)
            a[m] = *(const bf16x8*)&lds[arow + (m + 4) * 1024 + cg1];
        __builtin_amdgcn_s_barrier();
        asm volatile("s_waitcnt lgkmcnt(0)" ::: "memory");
        __builtin_amdgcn_sched_barrier(0);
        __builtin_amdgcn_s_setprio(1);
        MFMA_Q(4, a, b1);
        __builtin_amdgcn_s_setprio(0);
        if (u + 2 < NTK) {
            asm volatile("s_waitcnt vmcnt(4)" ::: "memory");  // leave B(u+2) in flight
        } else if (u + 1 < NTK) {
            asm volatile("s_waitcnt vmcnt(0)" ::: "memory");  // u==NTK-2: drain for last tile
        }
        __builtin_amdgcn_sched_barrier(0);
        __builtin_amdgcn_s_barrier();
    }

    // ---- epilogue ----
    const int orow0 = m0 + wm * 128;
    const int ocol0 = n0 + wn * 64;
    float bv[4];
#pragma unroll
    for (int n = 0; n < 4; ++n) bv[n] = bias[ocol0 + n * 16 + fr];
#pragma unroll
    for (int m = 0; m < 8; ++m)
#pragma unroll
        for (int n = 0; n < 4; ++n)
#pragma unroll
            for (int j = 0; j < 4; ++j)
                C[(size_t)(orow0 + m * 16 + hi * 4 + j) * N_DIM
                  + ocol0 + n * 16 + fr] = acc[m][n][j] + bv[n];
}

extern "C" void kernel_launch(void* const* d_in, const int* in_sizes, int n_in,
                              void* d_out, int out_size, void* d_ws, size_t ws_size,
                              hipStream_t stream) {
    const float* x     = (const float*)d_in[0];
    const float* w_loc = (const float*)d_in[1];
    const float* w_std = (const float*)d_in[2];
    const float* b_loc = (const float*)d_in[3];
    const float* b_std = (const float*)d_in[4];
    const float* eps_w = (const float*)d_in[5];
    const float* eps_b = (const float*)d_in[6];
    float* out = (float*)d_out;

    char* ws = (char*)d_ws;
    u16* Xb   = (u16*)ws;                                            // 64 MB
    u16* Wt   = (u16*)(ws + (size_t)M_DIM * K_DIM * 2);              // 32 MB
    float* bv = (float*)(ws + (size_t)M_DIM * K_DIM * 2
                            + (size_t)N_DIM * K_DIM * 2);            // 16 KB

    (void)hipFuncSetAttribute((const void*)gemm_kernel,
                              hipFuncAttributeMaxDynamicSharedMemorySize, 131072);

    conv_x_kernel<<<2048, 256, 0, stream>>>(x, Xb, (long long)M_DIM * K_DIM / 8);
    wconv_kernel<<<(K_DIM / 64) * (N_DIM / 64), 256, 0, stream>>>(w_loc, w_std, eps_w, Wt);
    bias_kernel<<<N_DIM / 256, 256, 0, stream>>>(b_loc, b_std, eps_b, bv);
    gemm_kernel<<<(M_DIM / 256) * (N_DIM / 256), 512, 131072, stream>>>(Xb, Wt, bv, out);
}